// Round 10
// baseline (534.965 us; speedup 1.0000x reference)
//
#include <hip/hip_runtime.h>
#include <hip/hip_cooperative_groups.h>
#include <math.h>

namespace cg = cooperative_groups;

#define N_NODES 20000
#define N_EDGES 4000
#define IN_DIM 128
#define NUM_HEADS 8
#define ALPHA 0.2f

#define HB_W 64      // u64 words per Hb row (e-bits): 4096 bits
#define HBT_W 320    // u64 words per HbT row (n-bits): 20480 bits
#define KPAD1 20480
#define KPAD2 4096
#define IPAD1 4096   // 16 blocks x 256 rows
#define IPAD2 20224  // 79 blocks x 256 rows
#define SPLITS1 32   // 640 k each = 5 stages of 128
#define SPLITS2 8    // 512 k each = 4 stages of 128

typedef float f32x4 __attribute__((ext_vector_type(4)));
typedef __bf16 bf16x8 __attribute__((ext_vector_type(8)));

// ---------- workspace layout (bytes) ----------
// Hb   : u64 [20000][64]   @ 0           10,240,000
// HbT  : u64 [4000][320]   @ 10,240,000  10,240,000
// VtT1 : bf16 [80][20480]  @ 20,480,000   3,276,800
// VtT2 : bf16 [64][4096]   @ 23,756,800     524,288
// expn : f32 [20000][8]    @ 24,281,088     640,000
// Yv   : f32 [20000][64]   @ 24,921,088   5,120,000
// P    : f32 partials      @ 30,041,088  41,943,040

__device__ __forceinline__ unsigned short f2b(float f) {  // fp32 -> bf16 RNE
    unsigned u = __float_as_uint(f);
    return (unsigned short)((u + 0x7FFFu + ((u >> 16) & 1u)) >> 16);
}
__device__ __forceinline__ bf16x8 expand8(unsigned b) {
    union { uint4 u; bf16x8 v; } cv;
    cv.u.x = ((b & 1u)   ? 0x3F80u : 0u) | ((b & 2u)   ? 0x3F800000u : 0u);
    cv.u.y = ((b & 4u)   ? 0x3F80u : 0u) | ((b & 8u)   ? 0x3F800000u : 0u);
    cv.u.z = ((b & 16u)  ? 0x3F80u : 0u) | ((b & 32u)  ? 0x3F800000u : 0u);
    cv.u.w = ((b & 64u)  ? 0x3F80u : 0u) | ((b & 128u) ? 0x3F800000u : 0u);
    return cv.v;
}
__device__ __forceinline__ bf16x8 ldsread(const unsigned short* p) {
    union { uint4 u; bf16x8 v; } cv;
    cv.u = *(const uint4*)p;
    return cv.v;
}

// ================= phase bodies (shared by mega + fallback kernels) =================

__device__ __forceinline__ void body_pack(int bid, int tid, const int* __restrict__ H,
                                          unsigned long long* __restrict__ Hb) {
    int wq = tid >> 6;
    int lane = tid & 63;
    int n = bid * 4 + wq;
    const int* hrow = H + (size_t)n * N_EDGES;
    unsigned long long* brow = Hb + (size_t)n * HB_W;
    int g = lane >> 4;
    int sh = 4 * (lane & 15);
    for (int it = 0; it < 16; it += 2) {
        int e0 = it * 256 + lane * 4;
        int e1 = e0 + 256;
        unsigned long long v0 = 0ull, v1 = 0ull;
        if (e0 < N_EDGES) {
            int4 v = *(const int4*)(hrow + e0);
            unsigned nb = (v.x > 0 ? 1u : 0u) | (v.y > 0 ? 2u : 0u) |
                          (v.z > 0 ? 4u : 0u) | (v.w > 0 ? 8u : 0u);
            v0 = (unsigned long long)nb << sh;
        }
        if (e1 < N_EDGES) {
            int4 v = *(const int4*)(hrow + e1);
            unsigned nb = (v.x > 0 ? 1u : 0u) | (v.y > 0 ? 2u : 0u) |
                          (v.z > 0 ? 4u : 0u) | (v.w > 0 ? 8u : 0u);
            v1 = (unsigned long long)nb << sh;
        }
        v0 |= __shfl_xor(v0, 1, 64);  v1 |= __shfl_xor(v1, 1, 64);
        v0 |= __shfl_xor(v0, 2, 64);  v1 |= __shfl_xor(v1, 2, 64);
        v0 |= __shfl_xor(v0, 4, 64);  v1 |= __shfl_xor(v1, 4, 64);
        v0 |= __shfl_xor(v0, 8, 64);  v1 |= __shfl_xor(v1, 8, 64);
        if ((lane & 15) == 0) {
            brow[it * 4 + g] = v0;
            brow[it * 4 + 4 + g] = v1;
        }
    }
}

__device__ __forceinline__ void body_fused1(int bid, int tid, const float* __restrict__ X,
                                            const float* __restrict__ W,
                                            const float* __restrict__ att,
                                            float* __restrict__ expn,
                                            float* __restrict__ Yv) {
    int t = bid * 256 + tid;
    int n = __builtin_amdgcn_readfirstlane(t >> 6);
    int d = t & 63;
    const float* x = X + (size_t)n * IN_DIM;
    float acc = 0.f;
#pragma unroll 8
    for (int k = 0; k < IN_DIM; k++) acc += x[k] * W[k * 64 + d];
    int h = d >> 3, j = d & 7;
    float av = att[h * 16 + j] + att[h * 16 + 8 + j];
    float v = acc * av;
    v += __shfl_xor(v, 1, 64);
    v += __shfl_xor(v, 2, 64);
    v += __shfl_xor(v, 4, 64);
    float s = (v >= 0.f) ? v : ALPHA * v;
    float e = expf(s);
    Yv[(size_t)n * 64 + d] = e * acc;
    if (j == 0) expn[(size_t)n * NUM_HEADS + h] = e;
}

__device__ __forceinline__ void body_transFE(int bid, int tid, float* tl /*[64][65]*/,
                                             const float* __restrict__ Yv,
                                             const float* __restrict__ expn,
                                             unsigned short* __restrict__ VtT1) {
    int n0 = bid * 64;
    int r = tid >> 2, s4 = tid & 3;
#pragma unroll
    for (int m = 0; m < 4; m++) {
        int cbase = s4 * 16 + m * 4;
        float4 v = make_float4(0.f, 0.f, 0.f, 0.f);
        if (n0 + r < N_NODES) v = *(const float4*)(Yv + (size_t)(n0 + r) * 64 + cbase);
        tl[r * 65 + cbase] = v.x; tl[r * 65 + cbase + 1] = v.y;
        tl[r * 65 + cbase + 2] = v.z; tl[r * 65 + cbase + 3] = v.w;
    }
    __syncthreads();
    int d = tid >> 2;
    unsigned short buf[16];
#pragma unroll
    for (int j = 0; j < 16; j++) buf[j] = f2b(tl[(s4 * 16 + j) * 65 + d]);
    uint4* o = (uint4*)(VtT1 + (size_t)d * KPAD1 + n0 + s4 * 16);
    o[0] = *(uint4*)&buf[0];
    o[1] = *(uint4*)&buf[8];
    int nl = tid & 63;
    int rw = tid >> 6;
#pragma unroll
    for (int p = 0; p < 4; p++) {
        int row = 64 + rw * 4 + p;
        float v = 0.f;
        if (row < 72 && n0 + nl < N_NODES) v = expn[(size_t)(n0 + nl) * NUM_HEADS + (row - 64)];
        VtT1[(size_t)row * KPAD1 + n0 + nl] = f2b(v);
    }
}

__device__ __forceinline__ void body_transB(int bx, int by, int tid,
                                            const unsigned long long* __restrict__ Hb,
                                            unsigned long long* __restrict__ HbT) {
    int wq = tid >> 6;
    int lane = tid & 63;
    int et = by * 4 + wq;
    if (et < 63) {
        int n0 = bx * 64;
        int n = n0 + lane;
        unsigned long long w = (n < N_NODES) ? Hb[(size_t)n * HB_W + et] : 0ull;
        unsigned long long out = 0ull;
#pragma unroll
        for (int c = 0; c < 64; c++) {
            unsigned long long bb = __ballot((w >> c) & 1ull);
            if (lane == c) out = bb;
        }
        int e = et * 64 + lane;
        if (e < N_EDGES) HbT[(size_t)e * HBT_W + bx] = out;
    }
}

template <int NCT>
__device__ __forceinline__ void body_mm(int bx, int by, int tid, unsigned short* VldsF,
                                        const unsigned long long* __restrict__ bits,
                                        int stride, int I,
                                        const unsigned short* __restrict__ Vg,
                                        int Kpad, int kPerSplit,
                                        float* __restrict__ P, int Ipad) {
    const int l = tid & 63;
    const int w = tid >> 6;
    const int q = l >> 4;
    const int cl = l & 15;
    const int rowbase = bx * 256 + w * 64;
    const int k0 = by * kPerSplit;
    const int nstages = kPerSplit >> 7;

    const unsigned long long* bp[4];
#pragma unroll
    for (int rt = 0; rt < 4; rt++) {
        int r = rowbase + rt * 16 + cl;
        if (r >= I) r = I - 1;
        bp[rt] = bits + (size_t)r * stride;
    }

    f32x4 acc[4][NCT];
#pragma unroll
    for (int rt = 0; rt < 4; rt++)
#pragma unroll
        for (int c = 0; c < NCT; c++) acc[rt][c] = (f32x4){0.f, 0.f, 0.f, 0.f};

    for (int st = 0; st < nstages; st++) {
        int kc = k0 + st * 128;
        __syncthreads();
#pragma unroll
        for (int c = 0; c < NCT; c++) {
            uint4 val = *(const uint4*)(Vg + (size_t)(c * 16 + cl) * Kpad + kc + (w * 4 + q) * 8);
            *(uint4*)&VldsF[(((c * 4 + w) * 64) + l) * 8] = val;
        }
        ulonglong2 wb[4];
#pragma unroll
        for (int rt = 0; rt < 4; rt++) wb[rt] = *(const ulonglong2*)(bp[rt] + (kc >> 6));
        __syncthreads();
#pragma unroll
        for (int kf = 0; kf < 4; kf++) {
            bf16x8 a[4];
#pragma unroll
            for (int rt = 0; rt < 4; rt++) {
                unsigned long long wsel = (kf < 2) ? wb[rt].x : wb[rt].y;
                unsigned byte = (unsigned)(wsel >> ((kf & 1) * 32 + q * 8)) & 0xFFu;
                a[rt] = expand8(byte);
            }
#pragma unroll
            for (int c = 0; c < NCT; c++) {
                bf16x8 bv = ldsread(&VldsF[(((c * 4 + kf) * 64) + l) * 8]);
#pragma unroll
                for (int rt = 0; rt < 4; rt++)
                    acc[rt][c] = __builtin_amdgcn_mfma_f32_16x16x32_bf16(a[rt], bv, acc[rt][c], 0, 0, 0);
            }
        }
    }

    size_t base = (size_t)by * Ipad;
#pragma unroll
    for (int rt = 0; rt < 4; rt++)
#pragma unroll
        for (int c = 0; c < NCT; c++)
#pragma unroll
            for (int r = 0; r < 4; r++)
                P[(base + rowbase + rt * 16 + q * 4 + r) * (NCT * 16) + c * 16 + cl] = acc[rt][c][r];
}

__device__ __forceinline__ void body_aggT(int bid, int tid, float* tl /*[64][65]*/,
                                          const float* __restrict__ P1,
                                          unsigned short* __restrict__ VtT2) {
    int e0 = bid * 64;
    int el = tid >> 2, s4 = tid & 3;
    int e = e0 + el;
    float num[16];
#pragma unroll
    for (int j = 0; j < 16; j++) num[j] = 0.f;
    float den0 = 0.f, den1 = 0.f;
    for (int sp = 0; sp < SPLITS1; sp++) {
        const float* row = P1 + ((size_t)sp * IPAD1 + e) * 80;
        const float4* r4 = (const float4*)(row + s4 * 16);
        float4 a = r4[0], b = r4[1], c = r4[2], d = r4[3];
        num[0] += a.x;  num[1] += a.y;  num[2] += a.z;  num[3] += a.w;
        num[4] += b.x;  num[5] += b.y;  num[6] += b.z;  num[7] += b.w;
        num[8] += c.x;  num[9] += c.y;  num[10] += c.z; num[11] += c.w;
        num[12] += d.x; num[13] += d.y; num[14] += d.z; num[15] += d.w;
        float2 dn = *(const float2*)(row + 64 + s4 * 2);
        den0 += dn.x; den1 += dn.y;
    }
#pragma unroll
    for (int j = 0; j < 16; j++) {
        float den = (j < 8) ? den0 : den1;
        float v = (e < N_EDGES && den > 0.f) ? num[j] / den : 0.f;
        tl[el * 65 + s4 * 16 + j] = v;
    }
    __syncthreads();
    int d = tid >> 2;
    unsigned short buf[16];
#pragma unroll
    for (int j = 0; j < 16; j++) buf[j] = f2b(tl[(s4 * 16 + j) * 65 + d]);
    uint4* o = (uint4*)(VtT2 + (size_t)d * KPAD2 + e0 + s4 * 16);
    o[0] = *(uint4*)&buf[0];
    o[1] = *(uint4*)&buf[8];
}

__device__ __forceinline__ void body_final4(int bid, int tid, const float* __restrict__ P2,
                                            const float* __restrict__ bias,
                                            float* __restrict__ out) {
    int t = bid * 256 + tid;
    int n = t >> 4, c4 = t & 15;
    float4 v = *(const float4*)(bias + c4 * 4);
#pragma unroll
    for (int sp = 0; sp < SPLITS2; sp++) {
        float4 p = *(const float4*)(P2 + ((size_t)sp * IPAD2 + n) * 64 + c4 * 4);
        v.x += p.x; v.y += p.y; v.z += p.z; v.w += p.w;
    }
    *(float4*)(out + (size_t)n * 64 + c4 * 4) = v;
}

// ================= mega: whole pipeline, one cooperative launch =================
__global__ void __launch_bounds__(256) mega(const int* __restrict__ H,
                                            unsigned long long* __restrict__ Hb,
                                            unsigned long long* __restrict__ HbT,
                                            const float* __restrict__ X,
                                            const float* __restrict__ W,
                                            const float* __restrict__ att,
                                            const float* __restrict__ bias,
                                            unsigned short* __restrict__ VtT1,
                                            unsigned short* __restrict__ VtT2,
                                            float* __restrict__ expn,
                                            float* __restrict__ Yv,
                                            float* __restrict__ P,
                                            float* __restrict__ out) {
    __shared__ __align__(16) char smem[20480];  // max(mm NCT=5: 20480, transFE/aggT: 16640)
    cg::grid_group grid = cg::this_grid();
    const int tid = threadIdx.x;
    const int G = gridDim.x;

    // Phase P: pack (even v) || fused1 (odd v), 10000 vblocks
    for (int v = blockIdx.x; v < 10000; v += G) {
        if ((v & 1) == 0) body_pack(v >> 1, tid, H, Hb);
        else              body_fused1(v >> 1, tid, X, W, att, expn, Yv);
    }
    grid.sync();
    // Phase T: transFE (0..319) || transB (320..5327)
    for (int v = blockIdx.x; v < 5328; v += G) {
        if (v < 320) body_transFE(v, tid, (float*)smem, Yv, expn, VtT1);
        else { int b = v - 320; body_transB(b % 313, b / 313, tid, Hb, HbT); }
        __syncthreads();  // smem reuse across v-iterations
    }
    grid.sync();
    // Phase M1: pass1 GEMM, 16 x SPLITS1 vblocks
    for (int v = blockIdx.x; v < 16 * SPLITS1; v += G)
        body_mm<5>(v % 16, v / 16, tid, (unsigned short*)smem, HbT, HBT_W, N_EDGES,
                   VtT1, KPAD1, KPAD1 / SPLITS1, P, IPAD1);
    grid.sync();
    // Phase G: aggT, 64 vblocks
    for (int v = blockIdx.x; v < 64; v += G) {
        body_aggT(v, tid, (float*)smem, P, VtT2);
        __syncthreads();
    }
    grid.sync();
    // Phase M2: pass2 GEMM, 79 x SPLITS2 vblocks
    for (int v = blockIdx.x; v < 79 * SPLITS2; v += G)
        body_mm<4>(v % 79, v / 79, tid, (unsigned short*)smem, Hb, HB_W, N_NODES,
                   VtT2, KPAD2, KPAD2 / SPLITS2, P, IPAD2);
    grid.sync();
    // Phase F: final, 1250 vblocks
    for (int v = blockIdx.x; v < 1250; v += G)
        body_final4(v, tid, P, bias, out);
}

// ================= fallback standalone kernels (R9 path) =================
__global__ void __launch_bounds__(256) kA(const int* __restrict__ H,
                                          unsigned long long* __restrict__ Hb,
                                          const float* __restrict__ X,
                                          const float* __restrict__ W,
                                          const float* __restrict__ att,
                                          float* __restrict__ expn,
                                          float* __restrict__ Yv) {
    if ((blockIdx.x & 1) == 0) body_pack(blockIdx.x >> 1, threadIdx.x, H, Hb);
    else body_fused1(blockIdx.x >> 1, threadIdx.x, X, W, att, expn, Yv);
}
__global__ void __launch_bounds__(256) kB(const unsigned long long* __restrict__ Hb,
                                          unsigned long long* __restrict__ HbT,
                                          const float* __restrict__ Yv,
                                          const float* __restrict__ expn,
                                          unsigned short* __restrict__ VtT1) {
    __shared__ float tl[64 * 65];
    if (blockIdx.x < 320) body_transFE(blockIdx.x, threadIdx.x, tl, Yv, expn, VtT1);
    else { int b = blockIdx.x - 320; body_transB(b % 313, b / 313, threadIdx.x, Hb, HbT); }
}
template <int NCT>
__global__ void __launch_bounds__(256) k_mm(const unsigned long long* __restrict__ bits,
                                            int stride, int I,
                                            const unsigned short* __restrict__ Vg,
                                            int Kpad, int kPerSplit,
                                            float* __restrict__ P, int Ipad) {
    __shared__ __align__(16) unsigned short VldsF[NCT * 4 * 64 * 8];
    body_mm<NCT>(blockIdx.x, blockIdx.y, threadIdx.x, VldsF, bits, stride, I, Vg, Kpad, kPerSplit, P, Ipad);
}
__global__ void __launch_bounds__(256) k_aggT(const float* __restrict__ P1,
                                              unsigned short* __restrict__ VtT2) {
    __shared__ float tl[64 * 65];
    body_aggT(blockIdx.x, threadIdx.x, tl, P1, VtT2);
}
__global__ void __launch_bounds__(256) k_final4(const float* __restrict__ P2,
                                                const float* __restrict__ bias,
                                                float* __restrict__ out) {
    body_final4(blockIdx.x, threadIdx.x, P2, bias, out);
}

extern "C" void kernel_launch(void* const* d_in, const int* in_sizes, int n_in,
                              void* d_out, int out_size, void* d_ws, size_t ws_size,
                              hipStream_t stream) {
    const int* H = (const int*)d_in[1];
    const float* X = (const float*)d_in[0];
    const float* W = (const float*)d_in[2];
    const float* att = (const float*)d_in[3];
    const float* bias = (const float*)d_in[4];
    float* out = (float*)d_out;

    char* ws = (char*)d_ws;
    unsigned long long* Hb  = (unsigned long long*)(ws + 0);
    unsigned long long* HbT = (unsigned long long*)(ws + 10240000);
    unsigned short* VtT1 = (unsigned short*)(ws + 20480000);
    unsigned short* VtT2 = (unsigned short*)(ws + 23756800);
    float* expn = (float*)(ws + 24281088);
    float* Yv   = (float*)(ws + 24921088);
    float* P    = (float*)(ws + 30041088);

    // Try the single cooperative mega-kernel (deterministic decision per call).
    hipError_t err = hipErrorUnknown;
    int maxB = 0;
    if (hipOccupancyMaxActiveBlocksPerMultiprocessor(&maxB, (const void*)mega, 256, 0) == hipSuccess
        && maxB > 0) {
        int grid = maxB * 256;          // 256 CUs on MI355X
        if (grid > 2048) grid = 2048;
        void* args[] = {(void*)&H, (void*)&Hb, (void*)&HbT, (void*)&X, (void*)&W,
                        (void*)&att, (void*)&bias, (void*)&VtT1, (void*)&VtT2,
                        (void*)&expn, (void*)&Yv, (void*)&P, (void*)&out};
        err = hipLaunchCooperativeKernel((const void*)mega, dim3(grid), dim3(256),
                                         args, 0, stream);
    }
    if (err != hipSuccess) {
        // Fallback: R9's measured-good 6-launch path.
        kA<<<10000, 256, 0, stream>>>(H, Hb, X, W, att, expn, Yv);
        kB<<<5328, 256, 0, stream>>>(Hb, HbT, Yv, expn, VtT1);
        k_mm<5><<<dim3(16, SPLITS1), 256, 0, stream>>>(HbT, HBT_W, N_EDGES, VtT1,
                                                       KPAD1, KPAD1 / SPLITS1, P, IPAD1);
        k_aggT<<<64, 256, 0, stream>>>(P, VtT2);
        k_mm<4><<<dim3(79, SPLITS2), 256, 0, stream>>>(Hb, HB_W, N_NODES, VtT2,
                                                       KPAD2, KPAD2 / SPLITS2, P, IPAD2);
        k_final4<<<1250, 256, 0, stream>>>(P, bias, out);
    }
}